// Round 5
// baseline (62.519 us; speedup 1.0000x reference)
//
#include <hip/hip_runtime.h>
#include <math.h>

#define H 8
#define B 64
#define D 512
#define EPS 1e-8f
#define INV_SQRT_D 0.04419417382415922f   // 1/sqrt(512)
#define LN2 0.6931471805599453f
#define EPS_LN2 6.931471805599453e-9f     // EPS * ln(2)
#define CUTOFF 34.0f                      // drop weights below 2^-34
#define TMAX_FALLBACK 36.0f               // flat softmax -> exact full scan

__device__ __forceinline__ float fast_rcp(float x) { return __builtin_amdgcn_rcpf(x); }
__device__ __forceinline__ float fast_exp2(float x) { return __builtin_amdgcn_exp2f(x); }

// ---------------------------------------------------------------------------
// Nearest-neighbor kernel: one block per (h,b), 512 threads.
// 1) stage q,v in LDS; 2) bitonic-sort (q,v) by q; 3) each thread (row i)
//    binary-searches k_i, gets exact dmin -> tmax, accumulates only the
//    window of j with weight >= 2^-CUTOFF. Exact full scan if softmax flat.
// ws: [H*B][D] attended rows (pre h-sum).
// ---------------------------------------------------------------------------
__global__ __launch_bounds__(512, 2) void attn_nn(
    const float* __restrict__ x,
    const float* __restrict__ Wq, const float* __restrict__ bq,
    const float* __restrict__ Wk, const float* __restrict__ bk,
    const float* __restrict__ Wv, const float* __restrict__ bv,
    float* __restrict__ ws)
{
    const int hb = blockIdx.x;          // 0..H*B-1
    const int h = hb >> 6;              // B == 64
    const int b = hb & 63;
    const int t = threadIdx.x;          // row i

    __shared__ float qs[D];
    __shared__ float vs[D];

    const float xv = x[b * D + t];
    qs[t] = Wq[h * D + t] * xv + bq[h * D + t];
    vs[t] = Wv[h * D + t] * xv + bv[h * D + t];
    const float ki = Wk[h * D + t] * xv + bk[h * D + t];
    __syncthreads();

    // Bitonic sort qs ascending, vs as payload (standard network, 45 stages)
    for (int k = 2; k <= D; k <<= 1) {
        for (int j = k >> 1; j > 0; j >>= 1) {
            const int ixj = t ^ j;
            if (ixj > t) {
                const float a0 = qs[t], a1 = qs[ixj];
                const bool up = ((t & k) == 0);
                if ((a0 > a1) == up) {
                    qs[t] = a1; qs[ixj] = a0;
                    const float v0 = vs[t], v1 = vs[ixj];
                    vs[t] = v1; vs[ixj] = v0;
                }
            }
            __syncthreads();
        }
    }

    // Binary search: p = number of qs[] < ki  (insertion point)
    int lo = 0, hi = D;
    while (lo < hi) {
        const int mid = (lo + hi) >> 1;
        if (qs[mid] < ki) lo = mid + 1; else hi = mid;
    }
    const int p = lo;

    const float dlo = (p > 0) ? (ki - qs[p - 1]) : INFINITY;
    const float dhi = (p < D) ? (qs[p] - ki) : INFINITY;
    const float dmin = fminf(dlo, dhi);
    const float tmax = fast_rcp(fmaf(dmin, LN2, EPS_LN2));

    float l = 0.f, a = 0.f;
    if (tmax < TMAX_FALLBACK) {
        // Flat softmax: exact full scan (rare; correctness for any data)
        for (int s = 0; s < D; ++s) {
            const float d = fabsf(qs[s] - ki);
            const float e = fast_exp2(fast_rcp(fmaf(d, LN2, EPS_LN2)) - tmax);
            l += e; a = fmaf(e, vs[s], a);
        }
    } else {
        // Window radius: T(d) >= tmax - CUTOFF  <=>  d <= rcp((tmax-C)*ln2)-eps
        const float rad = fast_rcp((tmax - CUTOFF) * LN2) * 1.001f;
        // scan down (d = ki - qs[s] >= 0 by sortedness)
        for (int s = p - 1; s >= 0; --s) {
            const float d = ki - qs[s];
            if (d > rad) break;
            const float e = fast_exp2(fast_rcp(fmaf(d, LN2, EPS_LN2)) - tmax);
            l += e; a = fmaf(e, vs[s], a);
        }
        // scan up (d = qs[s] - ki >= 0)
        for (int s = p; s < D; ++s) {
            const float d = qs[s] - ki;
            if (d > rad) break;
            const float e = fast_exp2(fast_rcp(fmaf(d, LN2, EPS_LN2)) - tmax);
            l += e; a = fmaf(e, vs[s], a);
        }
    }

    ws[hb * D + t] = a * fast_rcp(l) * INV_SQRT_D;
}

// out[b,i] = x[b,i] + sum_h ws[h,b,i]  (deterministic h-sum)
__global__ __launch_bounds__(256) void reduce_h(
    const float* __restrict__ x, const float* __restrict__ ws,
    float* __restrict__ out)
{
    const int i = blockIdx.x * 256 + threadIdx.x;   // 0..B*D-1
    float s = x[i];
    #pragma unroll
    for (int h = 0; h < H; ++h) s += ws[h * (B * D) + i];
    out[i] = s;
}

// ---------------------------------------------------------------------------
// Fallback (no ws): fully fused exact kernel.
// ---------------------------------------------------------------------------
__global__ __launch_bounds__(512) void attn_fused(
    const float* __restrict__ x,
    const float* __restrict__ Wq, const float* __restrict__ bq,
    const float* __restrict__ Wk, const float* __restrict__ bk,
    const float* __restrict__ Wv, const float* __restrict__ bv,
    float* __restrict__ out)
{
    const int b = blockIdx.x;
    const int t = threadIdx.x;

    __shared__ float qs[D];
    __shared__ float vs[D];

    const float xv = x[b * D + t];
    float total = 0.f;

    for (int h = 0; h < H; ++h) {
        __syncthreads();
        qs[t] = Wq[h * D + t] * xv + bq[h * D + t];
        vs[t] = Wv[h * D + t] * xv + bv[h * D + t];
        const float ki = Wk[h * D + t] * xv + bk[h * D + t];
        __syncthreads();

        const float4* q4 = reinterpret_cast<const float4*>(qs);
        const float4* v4 = reinterpret_cast<const float4*>(vs);

        float d0 = INFINITY, d1 = INFINITY, d2 = INFINITY, d3 = INFINITY;
        for (int j = 0; j < D / 4; ++j) {
            float4 q = q4[j];
            d0 = fminf(d0, fabsf(q.x - ki));
            d1 = fminf(d1, fabsf(q.y - ki));
            d2 = fminf(d2, fabsf(q.z - ki));
            d3 = fminf(d3, fabsf(q.w - ki));
        }
        const float dmin = fminf(fminf(d0, d1), fminf(d2, d3));
        const float tmax = fast_rcp(fmaf(dmin, LN2, EPS_LN2));

        float l0 = 0.f, l1 = 0.f, l2 = 0.f, l3 = 0.f;
        float a0 = 0.f, a1 = 0.f, a2 = 0.f, a3 = 0.f;
        for (int j = 0; j < D / 4; ++j) {
            float4 q = q4[j];
            float4 v = v4[j];
            float e0 = fast_exp2(fast_rcp(fmaf(fabsf(q.x - ki), LN2, EPS_LN2)) - tmax);
            float e1 = fast_exp2(fast_rcp(fmaf(fabsf(q.y - ki), LN2, EPS_LN2)) - tmax);
            float e2 = fast_exp2(fast_rcp(fmaf(fabsf(q.z - ki), LN2, EPS_LN2)) - tmax);
            float e3 = fast_exp2(fast_rcp(fmaf(fabsf(q.w - ki), LN2, EPS_LN2)) - tmax);
            l0 += e0; a0 = fmaf(e0, v.x, a0);
            l1 += e1; a1 = fmaf(e1, v.y, a1);
            l2 += e2; a2 = fmaf(e2, v.z, a2);
            l3 += e3; a3 = fmaf(e3, v.w, a3);
        }
        const float l = (l0 + l1) + (l2 + l3);
        const float a = (a0 + a1) + (a2 + a3);
        total += a * fast_rcp(l) * INV_SQRT_D;
    }
    out[b * D + t] = xv + total;
}

extern "C" void kernel_launch(void* const* d_in, const int* in_sizes, int n_in,
                              void* d_out, int out_size, void* d_ws, size_t ws_size,
                              hipStream_t stream) {
    const float* x  = (const float*)d_in[0];
    const float* Wq = (const float*)d_in[1];
    const float* bq = (const float*)d_in[2];
    const float* Wk = (const float*)d_in[3];
    const float* bk = (const float*)d_in[4];
    const float* Wv = (const float*)d_in[5];
    const float* bv = (const float*)d_in[6];
    float* out = (float*)d_out;

    const size_t need = (size_t)H * B * D * sizeof(float);   // 1 MB

    if (ws_size >= need) {
        float* ws = (float*)d_ws;
        attn_nn<<<H * B, 512, 0, stream>>>(x, Wq, bq, Wk, bk, Wv, bv, ws);
        reduce_h<<<(B * D) / 256, 256, 0, stream>>>(x, ws, out);
    } else {
        attn_fused<<<B, 512, 0, stream>>>(x, Wq, bq, Wk, bk, Wv, bv, out);
    }
}